// Round 14
// baseline (25.481 us; speedup 1.0000x reference)
//
#include <hip/hip_runtime.h>

// ColorReducer: per-pixel argmin_k of d2 = (x2 - 2*cross) + p2, bit-exact vs
// numpy reference: cross = ((r*pr + g*pg) + b*pb), x2 = ((r*r+g*g)+b*b),
// d2 = (x2 - 2*cross) + p2, first-index tie-break (strict <).
//
// Exactness (verified R0/R2/R3/R5..R12, absmax 0.0): contract(off);
// pre-doubled pixels (fl(2r*pr)=2*fl(r*pr), fl(2x+2y)=2*fl(x+y) exact);
// k=0 seed == +inf seed with strict <; packed v2f per-element IEEE RN.
// BANNED: nt stores (R1); readfirstlane arrays (R4); launch_bounds cap
// (R4/R6); PPT=2 (R7); PPT=8 (R12 null); half-residency (R3);
// setprio/LDS-p2 (R10); mid-loop fenced loads (R11); upfront prefetch (R8).
//
// R13 theory: R9 showed EXACT additivity (23.6+28.6=52.2) and trickle BW
// (1.2 TB/s) -> all waves phase-lock (load burst / compute / store burst in
// lockstep). Every prior attempt rearranged instructions WITHIN lockstep.
// This round de-phases the waves themselves: wave-uniform staggered s_sleep
// prologue (slot = (blockIdx*4+wid)&7, slot x ~0.37us, spread ~2.6us) turns
// the grid's load burst into a steady stream that runs under other waves'
// compute. Math/structure = R5 verbatim.

typedef float v2f __attribute__((ext_vector_type(2)));

constexpr int HW    = 512 * 512;   // 2^18
constexpr int KCOL  = 16;
constexpr long NPIX = 16L * HW;    // 4,194,304
constexpr int PPT   = 4;

__global__ __launch_bounds__(256) void color_reduce_kernel(
    const float* __restrict__ x,       // (B, 3, H, W)
    const float* __restrict__ pal,     // (16, 3)
    float* __restrict__ out)           // (B, 3, H, W)
{
#pragma clang fp contract(off)
    __shared__ float spal[KCOL * 3];
    if (threadIdx.x < KCOL * 3) spal[threadIdx.x] = pal[threadIdx.x];
    __syncthreads();

    // ---- wave de-phasing stagger (R13): wave-uniform, deterministic ----
    {
        const int slot = ((blockIdx.x << 2) + (threadIdx.x >> 6)) & 7;
        for (int i = 0; i < slot; ++i)
            __builtin_amdgcn_s_sleep(14);   // 14*64 = 896 cyc ~= 0.37 us
    }

    const long t  = (long)blockIdx.x * blockDim.x + threadIdx.x;
    const long n0 = t * PPT;
    const int b   = (int)(n0 >> 18);        // n0 / HW
    const int pix = (int)(n0 & (HW - 1));   // n0 % HW

    const float* base = x + (size_t)b * 3 * HW + pix;
    const float4 rv = *reinterpret_cast<const float4*>(base);
    const float4 gv = *reinterpret_cast<const float4*>(base + HW);
    const float4 bv = *reinterpret_cast<const float4*>(base + 2 * HW);

    const v2f rA = {rv.x, rv.y}, rB = {rv.z, rv.w};
    const v2f gA = {gv.x, gv.y}, gB = {gv.z, gv.w};
    const v2f bA = {bv.x, bv.y}, bB = {bv.z, bv.w};

    const v2f x2A = ((rA * rA) + (gA * gA)) + (bA * bA);
    const v2f x2B = ((rB * rB) + (gB * gB)) + (bB * bB);

    const v2f r2A = rA + rA, g2A = gA + gA, b2A = bA + bA;
    const v2f r2B = rB + rB, g2B = gB + gB, b2B = bB + bB;

    float best0, best1, best2, best3;
    int   k0 = 0, k1 = 0, k2 = 0, k3 = 0;

    {   // k = 0 seeds best (== +inf seed with strict <)
        const float pr = pal[0], pg = pal[1], pb = pal[2];
        const float p2 = ((pr * pr) + (pg * pg)) + (pb * pb);
        const v2f prv = {pr, pr}, pgv = {pg, pg}, pbv = {pb, pb}, p2v = {p2, p2};
        const v2f crA = ((r2A * prv) + (g2A * pgv)) + (b2A * pbv);  // == 2*cross
        const v2f crB = ((r2B * prv) + (g2B * pgv)) + (b2B * pbv);
        const v2f dA  = (x2A - crA) + p2v;
        const v2f dB  = (x2B - crB) + p2v;
        best0 = dA.x; best1 = dA.y; best2 = dB.x; best3 = dB.y;
    }

#pragma unroll
    for (int k = 1; k < KCOL; ++k) {
        const float pr = pal[3 * k + 0];   // uniform -> s_load/SGPR
        const float pg = pal[3 * k + 1];
        const float pb = pal[3 * k + 2];
        const float p2 = ((pr * pr) + (pg * pg)) + (pb * pb);
        const v2f prv = {pr, pr}, pgv = {pg, pg}, pbv = {pb, pb}, p2v = {p2, p2};
        const v2f crA = ((r2A * prv) + (g2A * pgv)) + (b2A * pbv);
        const v2f crB = ((r2B * prv) + (g2B * pgv)) + (b2B * pbv);
        const v2f dA  = (x2A - crA) + p2v;
        const v2f dB  = (x2B - crB) + p2v;
        if (dA.x < best0) { best0 = dA.x; k0 = k; }   // strict <: np.argmin
        if (dA.y < best1) { best1 = dA.y; k1 = k; }
        if (dB.x < best2) { best2 = dB.x; k2 = k; }
        if (dB.y < best3) { best3 = dB.y; k3 = k; }
    }

    // Gather winning colors from LDS palette.
    const float o0r = spal[3 * k0 + 0], o0g = spal[3 * k0 + 1], o0b = spal[3 * k0 + 2];
    const float o1r = spal[3 * k1 + 0], o1g = spal[3 * k1 + 1], o1b = spal[3 * k1 + 2];
    const float o2r = spal[3 * k2 + 0], o2g = spal[3 * k2 + 1], o2b = spal[3 * k2 + 2];
    const float o3r = spal[3 * k3 + 0], o3g = spal[3 * k3 + 1], o3b = spal[3 * k3 + 2];

    float* ob = out + (size_t)b * 3 * HW + pix;
    *reinterpret_cast<float4*>(ob)          = make_float4(o0r, o1r, o2r, o3r);
    *reinterpret_cast<float4*>(ob + HW)     = make_float4(o0g, o1g, o2g, o3g);
    *reinterpret_cast<float4*>(ob + 2 * HW) = make_float4(o0b, o1b, o2b, o3b);
}

extern "C" void kernel_launch(void* const* d_in, const int* in_sizes, int n_in,
                              void* d_out, int out_size, void* d_ws, size_t ws_size,
                              hipStream_t stream) {
    const float* x   = (const float*)d_in[0];
    const float* pal = (const float*)d_in[1];
    float* out       = (float*)d_out;

    const int threads = 256;
    const long total_threads = NPIX / PPT;              // 1,048,576
    const int blocks = (int)(total_threads / threads);  // 4096
    color_reduce_kernel<<<blocks, threads, 0, stream>>>(x, pal, out);
}